// Round 12
// baseline (363.148 us; speedup 1.0000x reference)
//
#include <hip/hip_runtime.h>
#include <cstdint>
#include <math.h>

typedef unsigned long long u64;

// ---------------------------------------------------------------------------
// Activation bit-maps are CW-PLANE-MAJOR and zero-padded:
//   map[((cw*128 + b)*Hp + y)*Wp + x],  Hp=H+2, Wp=W+2, halo = 0
// Weights packed COMPLEMENTED, per-oc contiguous:
//   wq[(oc*WI + cw)*9 + tap],  bit i = !(w[tap][cw*64+i][oc] > 0)
// meta[oc*12 + k]: k=0..3 -> A,B,C,D (top/bot/left/right orig-popcount sums)
//                  k=4..7 -> p0,p2,p6,p8 (corner taps), k=8 -> ithr
// ---------------------------------------------------------------------------

// guaranteed fused popcount-accumulate: exactly 2 VALU inst per u64
__device__ __forceinline__ int bcnt2(u64 x, int acc) {
    int r;
    asm("v_bcnt_u32_b32 %0, %1, %3\n\t"
        "v_bcnt_u32_b32 %0, %2, %0"
        : "=&v"(r)
        : "v"((unsigned)x), "v"((unsigned)(x >> 32)), "v"(acc));
    return r;
}

// ---------------------------------------------------------------------------
// prep: (a) zero padded maps (blocks [0,1024));
//       (b) pack 5 binary weight tensors (complemented, per-oc contiguous);
//       (c) meta per oc from FLOAT weights (no dependency on (b)).
// ---------------------------------------------------------------------------
__global__ __launch_bounds__(256) void prep_kernel(
        const float* __restrict__ w2, const float* __restrict__ w3,
        const float* __restrict__ w4, const float* __restrict__ w5,
        const float* __restrict__ w6,
        u64* __restrict__ wq2, u64* __restrict__ wq3, u64* __restrict__ wq4,
        u64* __restrict__ wq5, u64* __restrict__ wq6,
        const float* s2, const float* b2, const float* s3, const float* b3,
        const float* s4, const float* b4, const float* s5, const float* b5,
        const float* s6, const float* b6,
        int* __restrict__ mt, u64* __restrict__ pz, int nz) {
    const int ZB = 1024;
    if (blockIdx.x < ZB) {
        int i = blockIdx.x * 256 + threadIdx.x;
        const int stride = ZB * 256;
        for (; i < nz; i += stride) pz[i] = 0;
        return;
    }
    int wid = ((blockIdx.x - ZB) * 256 + threadIdx.x) >> 6;
    int lane = threadIdx.x & 63;
    if (wid < 71424) {
        // ---- weight packing ----
        const float* w; u64* wq; int Wi, Cout, base;
        if      (wid <  2304) { w = w2; wq = wq2; Wi = 2; Cout = 128; base = 0; }
        else if (wid <  6912) { w = w3; wq = wq3; Wi = 2; Cout = 256; base = 2304; }
        else if (wid < 16128) { w = w4; wq = wq4; Wi = 4; Cout = 256; base = 6912; }
        else if (wid < 34560) { w = w5; wq = wq5; Wi = 4; Cout = 512; base = 16128; }
        else                  { w = w6; wq = wq6; Wi = 8; Cout = 512; base = 34560; }
        int id = wid - base;
        int oc = id % Cout;
        int tw = id / Cout;            // tap*Wi + cw
        int tap = tw / Wi, cw = tw % Wi;
        int Cin = Wi * 64;
        float v = w[((size_t)tap * Cin + cw * 64 + lane) * Cout + oc];
        u64 mask = __ballot(!(v > 0.0f));
        if (lane == 0) wq[((size_t)oc * Wi + cw) * 9 + tap] = mask;
    } else if (wid < 71424 + 1664) {
        // ---- meta from float weights: one wave per oc ----
        int id2 = wid - 71424;
        const float* w; const float* sc; const float* bi; int Wi, Cout, oc, mbase;
        if      (id2 <  128) { w = w2; Wi = 2; Cout = 128; oc = id2;        mbase = 0;     sc = s2; bi = b2; }
        else if (id2 <  384) { w = w3; Wi = 2; Cout = 256; oc = id2 - 128;  mbase = 1536;  sc = s3; bi = b3; }
        else if (id2 <  640) { w = w4; Wi = 4; Cout = 256; oc = id2 - 384;  mbase = 4608;  sc = s4; bi = b4; }
        else if (id2 < 1152) { w = w5; Wi = 4; Cout = 512; oc = id2 - 640;  mbase = 7680;  sc = s5; bi = b5; }
        else                 { w = w6; Wi = 8; Cout = 512; oc = id2 - 1152; mbase = 13824; sc = s6; bi = b6; }
        int Cin = Wi * 64;
        int P[9];
        #pragma unroll
        for (int tap = 0; tap < 9; tap++) {
            int cnt = 0;
            for (int cw = 0; cw < Wi; cw++) {
                float v = w[((size_t)tap * Cin + cw * 64 + lane) * Cout + oc];
                cnt += (int)__popcll(__ballot(v > 0.0f));
            }
            P[tap] = cnt;
        }
        if (lane == 0) {
            int* mo = mt + mbase + oc * 12;
            mo[0] = P[0] + P[1] + P[2];    // top
            mo[1] = P[6] + P[7] + P[8];    // bottom
            mo[2] = P[0] + P[3] + P[6];    // left
            mo[3] = P[2] + P[5] + P[8];    // right
            mo[4] = P[0]; mo[5] = P[2]; mo[6] = P[6]; mo[7] = P[8];
            double tneg = -(double)bi[oc] / (double)sc[oc];
            mo[8] = (tneg < 0.0) ? -(1 << 29) : (int)floor(tneg);
        }
    }
}

// ---------------------------------------------------------------------------
// conv1 (float, 3->128) + b1 + relu + bn1 -> sign bits into plane-major
// padded p1. Weights in VGPRs, 8 px/thread sliding window. Double
// accumulation: sign decisions feed 5 binary layers; must be exact.
// ---------------------------------------------------------------------------
__global__ __launch_bounds__(128) void conv1_pack_kernel(
        const float* __restrict__ x, const float* __restrict__ w1,
        const float* __restrict__ b1, const float* __restrict__ s1,
        const float* __restrict__ bb1, u64* __restrict__ p1) {
    const int t = threadIdx.x;
    const int oc = t;
    const int bx = blockIdx.x;
    const int xseg = (bx & 3) << 3;    // 0,8,16,24
    const int y = (bx >> 2) & 31;
    const int b = bx >> 7;

    double wreg[27];
    #pragma unroll
    for (int k = 0; k < 27; k++) wreg[k] = (double)w1[k * 128 + oc];
    const double b1v = (double)b1[oc];
    const double tneg = -(double)bb1[oc] / (double)s1[oc];
    const bool always = tneg < 0.0;
    const double thr = tneg - b1v;

    double acc[8];
    #pragma unroll
    for (int i = 0; i < 8; i++) acc[i] = 0.0;

    #pragma unroll
    for (int ky = 0; ky < 3; ky++) {
        int iy = y - 1 + ky;
        if (iy < 0 || iy > 31) continue;
        #pragma unroll
        for (int col = 0; col < 10; col++) {
            int ix = xseg - 1 + col;
            if (ix < 0 || ix > 31) continue;
            const float* xp = x + ((b * 32 + iy) * 32 + ix) * 3;
            #pragma unroll
            for (int c = 0; c < 3; c++) {
                double xv = (double)xp[c];
                #pragma unroll
                for (int kx = 0; kx < 3; kx++) {
                    int px = col - kx;
                    if (px >= 0 && px < 8)
                        acc[px] += xv * wreg[(ky * 3 + kx) * 3 + c];
                }
            }
        }
    }
    const int w = t >> 6;   // cw plane
    #pragma unroll
    for (int px = 0; px < 8; px++) {
        bool bit = always || (acc[px] > thr);
        u64 m = __ballot(bit);
        if ((t & 63) == 0)
            p1[(((size_t)w * 128 + b) * 34 + y + 1) * 34 + xseg + px + 1] = m;
    }
}

// ---------------------------------------------------------------------------
// Binary conv v6.2 — lane = pixel, cw-outer streaming, OCG=8, asm-fused
// popcount accumulate (exactly 4 VALU per 64-MAC unit).
// One wave = 8x8 pre-pool tile x 8 channels; act[9] per cw; m[8] resident.
// Epilogue: d = 2*(m+S) - 64*WI*(9+n_oob); bit = d > ithr (int cmp);
// pooled mask = OR over window via 2 shfl_xor; byte store per group.
// ---------------------------------------------------------------------------
template<int WI, int H, int W, int COUT, bool POOL, bool BITOUT>
__global__ __launch_bounds__(256, 4) void bconv62_kernel(
        const u64* __restrict__ in, const u64* __restrict__ wq,
        const int* __restrict__ mt,
        const float* __restrict__ bns, const float* __restrict__ bnb,
        u64* __restrict__ outb, float* __restrict__ outf) {
    constexpr int OCG = 8;
    constexpr int Hp = H + 2, Wp = W + 2;
    constexpr int Ho = POOL ? H / 2 : H;
    constexpr int Wo = POOL ? W / 2 : W;
    constexpr int TX = W / 8;
    constexpr int TILES = (H / 8) * (W / 8);
    constexpr int NG = COUT / OCG;

    const int lane = threadIdx.x & 63;
    int wid = (blockIdx.x * blockDim.x + threadIdx.x) >> 6;
    wid = __builtin_amdgcn_readfirstlane(wid);
    const int g = wid % NG;
    int tb = wid / NG;
    const int tile = tb % TILES;
    const int b = tb / TILES;
    if (b >= 128) return;
    const int ly = lane >> 3, lx = lane & 7;
    const int py = (tile / TX) * 8 + ly;
    const int px = (tile % TX) * 8 + lx;
    const int oc0 = g * OCG;

    // per-lane edge flags / padding base
    const int ft = (py == 0), fb = (py == H - 1);
    const int fl = (px == 0), fr = (px == W - 1);
    const int ctl = ft & fl, ctr = ft & fr, cbl = fb & fl, cbr = fb & fr;
    const int n_oob = 3 * (ft + fb + fl + fr) - ctl - ctr - cbl - cbr;
    const int dbase = -64 * WI * (9 + n_oob);
    const bool anyedge = __ballot(ft | fb | fl | fr) != 0;

    int m[OCG];
    #pragma unroll
    for (int o = 0; o < OCG; o++) m[o] = 0;

    const u64* ab = in + ((size_t)b * Hp + py) * Wp + px;   // plane 0 base
    const u64* wb0 = wq + (size_t)oc0 * WI * 9;

    #pragma unroll 1
    for (int cw = 0; cw < WI; cw++) {
        const u64* ap = ab + (size_t)cw * (128 * Hp * Wp);
        u64 act[9];
        #pragma unroll
        for (int ky = 0; ky < 3; ky++)
            #pragma unroll
            for (int kx = 0; kx < 3; kx++)
                act[ky * 3 + kx] = ap[ky * Wp + kx];
        const u64* wb = wb0 + (size_t)cw * 9;
        #pragma unroll
        for (int o = 0; o < OCG; o++) {
            const u64* wl = wb + (size_t)o * (WI * 9);   // uniform -> s_load
            int acc = m[o];
            #pragma unroll
            for (int t9 = 0; t9 < 9; t9++)
                acc = bcnt2(act[t9] ^ wl[t9], acc);      // 4 VALU / unit
            m[o] = acc;
        }
    }

    // ---- epilogue ----
    const bool master = POOL ? (((ly | lx) & 1) == 0) : true;
    const int opy = POOL ? (py >> 1) : py, opx = POOL ? (px >> 1) : px;
    unsigned mask = 0;

    #pragma unroll
    for (int o = 0; o < OCG; o++) {
        const int* mo = mt + (size_t)(oc0 + o) * 12;
        int d;
        if (anyedge) {
            int S = ft * mo[0] + fb * mo[1] + fl * mo[2] + fr * mo[3]
                  - ctl * mo[4] - ctr * mo[5] - cbl * mo[6] - cbr * mo[7];
            d = 2 * (m[o] + S) + dbase;
        } else {
            d = 2 * m[o] - 64 * WI * 9;
        }
        if constexpr (BITOUT) {
            mask |= (unsigned)(d > mo[8]) << o;
        } else {
            int dm = max(d, __shfl_xor(d, 1, 64));
            int dp = max(dm, __shfl_xor(dm, 8, 64));
            int pmax = dp > 0 ? dp : 0;
            float h = (float)pmax * bns[oc0 + o] + bnb[oc0 + o];
            if (master)
                outf[(size_t)((b * 4 + opy) * 4 + opx) * 512 + oc0 + o] = h;
        }
    }

    if constexpr (BITOUT) {
        if constexpr (POOL) {
            mask |= __shfl_xor(mask, 1, 64);
            mask |= __shfl_xor(mask, 8, 64);
        }
        if (master) {
            size_t idx = (((size_t)(oc0 >> 6) * 128 + b) * (Ho + 2) + opy + 1)
                         * (Wo + 2) + opx + 1;
            char* bp = (char*)(outb + idx) + ((oc0 & 63) >> 3);
            *(unsigned char*)bp = (unsigned char)mask;
        }
    }
}

// ---------------------------------------------------------------------------
// Dense (512x10) + softmax. One wave per row. 2048 rows.
// ---------------------------------------------------------------------------
__global__ __launch_bounds__(256) void dense_softmax_kernel(
        const float* __restrict__ h6, const float* __restrict__ dw,
        const float* __restrict__ db, float* __restrict__ out) {
    int lane = threadIdx.x & 63;
    int r = (blockIdx.x * blockDim.x + threadIdx.x) >> 6;
    if (r >= 2048) return;
    const float* hr = h6 + (size_t)r * 512;
    float part[10];
    #pragma unroll
    for (int d = 0; d < 10; d++) part[d] = 0.f;
    #pragma unroll
    for (int k = 0; k < 8; k++) {
        int c = lane + 64 * k;
        float hv = hr[c];
        const float* dwr = dw + c * 10;
        #pragma unroll
        for (int d = 0; d < 10; d++) part[d] += hv * dwr[d];
    }
    #pragma unroll
    for (int off = 32; off >= 1; off >>= 1) {
        #pragma unroll
        for (int d = 0; d < 10; d++) part[d] += __shfl_down(part[d], off, 64);
    }
    if (lane == 0) {
        float logits[10];
        float mx = -1e30f;
        #pragma unroll
        for (int d = 0; d < 10; d++) { logits[d] = part[d] + db[d]; mx = fmaxf(mx, logits[d]); }
        float se = 0.f;
        #pragma unroll
        for (int d = 0; d < 10; d++) { logits[d] = expf(logits[d] - mx); se += logits[d]; }
        float inv = 1.f / se;
        #pragma unroll
        for (int d = 0; d < 10; d++) out[(size_t)r * 10 + d] = logits[d] * inv;
    }
}

// ---------------------------------------------------------------------------
extern "C" void kernel_launch(void* const* d_in, const int* in_sizes, int n_in,
                              void* d_out, int out_size, void* d_ws, size_t ws_size,
                              hipStream_t stream) {
    const float* x    = (const float*)d_in[0];
    const float* w1   = (const float*)d_in[1];
    const float* b1   = (const float*)d_in[2];
    const float* w2   = (const float*)d_in[3];
    const float* w3   = (const float*)d_in[4];
    const float* w4   = (const float*)d_in[5];
    const float* w5   = (const float*)d_in[6];
    const float* w6   = (const float*)d_in[7];
    const float* bn1s = (const float*)d_in[8];
    const float* bn1b = (const float*)d_in[9];
    const float* bn2s = (const float*)d_in[10];
    const float* bn2b = (const float*)d_in[11];
    const float* bn3s = (const float*)d_in[12];
    const float* bn3b = (const float*)d_in[13];
    const float* bn4s = (const float*)d_in[14];
    const float* bn4b = (const float*)d_in[15];
    const float* bn5s = (const float*)d_in[16];
    const float* bn5b = (const float*)d_in[17];
    const float* bn6s = (const float*)d_in[18];
    const float* bn6b = (const float*)d_in[19];
    const float* dw   = (const float*)d_in[20];
    const float* db   = (const float*)d_in[21];
    float* out = (float*)d_out;

    // workspace (u64 units)
    u64* ws   = (u64*)d_ws;
    u64* wq2  = ws;                    // 2304
    u64* wq3  = ws + 2304;             // 4608
    u64* wq4  = ws + 6912;             // 9216
    u64* wq5  = ws + 16128;            // 18432
    u64* wq6  = ws + 34560;            // 36864
    int* mt   = (int*)(ws + 71424);    // 19968 ints = 9984 u64
    u64* p1   = ws + 81408;            // 2*128*34*34 = 295936
    u64* p2   = ws + 377344;           // 2*128*18*18 = 82944
    u64* p3   = ws + 460288;           // 4*128*18*18 = 165888
    u64* p4   = ws + 626176;           // 4*128*10*10 = 51200
    u64* p5   = ws + 677376;           // 8*128*10*10 = 102400
    float* h6 = (float*)(ws + 779776); // 128*4*4*512 floats
    const int NPAD = 295936 + 82944 + 165888 + 51200 + 102400;  // 698368

    int* mt2 = mt + 0;
    int* mt3 = mt + 1536;
    int* mt4 = mt + 4608;
    int* mt5 = mt + 7680;
    int* mt6 = mt + 13824;

    // prep: zero maps + pack weights + meta; blocks = 1024 + (71424+1664)/4
    prep_kernel<<<1024 + 18272, 256, 0, stream>>>(
        w2, w3, w4, w5, w6, wq2, wq3, wq4, wq5, wq6,
        bn2s, bn2b, bn3s, bn3b, bn4s, bn4b, bn5s, bn5b, bn6s, bn6b,
        mt, p1, NPAD);

    conv1_pack_kernel<<<128*32*4, 128, 0, stream>>>(x, w1, b1, bn1s, bn1b, p1);

    // waves = 128 * tiles/img * (COUT/8); blocks = waves/4
    bconv62_kernel<2,32,32,128,true, true ><<<8192, 256, 0, stream>>>(p1, wq2, mt2, nullptr, nullptr, p2, nullptr);
    bconv62_kernel<2,16,16,256,false,true ><<<4096, 256, 0, stream>>>(p2, wq3, mt3, nullptr, nullptr, p3, nullptr);
    bconv62_kernel<4,16,16,256,true, true ><<<4096, 256, 0, stream>>>(p3, wq4, mt4, nullptr, nullptr, p4, nullptr);
    bconv62_kernel<4,8,8,  512,false,true ><<<2048, 256, 0, stream>>>(p4, wq5, mt5, nullptr, nullptr, p5, nullptr);
    bconv62_kernel<8,8,8,  512,true, false><<<2048, 256, 0, stream>>>(p5, wq6, mt6, bn6s, bn6b, nullptr, h6);

    dense_softmax_kernel<<<512, 256, 0, stream>>>(h6, dw, db, out);
}

// Round 13
// 319.545 us; speedup vs baseline: 1.1365x; 1.1365x over previous
//
#include <hip/hip_runtime.h>
#include <cstdint>
#include <math.h>

typedef unsigned long long u64;

// ---------------------------------------------------------------------------
// Activation bit-maps are CW-PLANE-MAJOR and zero-padded:
//   map[((cw*128 + b)*Hp + y)*Wp + x],  Hp=H+2, Wp=W+2, halo = 0
// Weights packed COMPLEMENTED, per-oc contiguous:
//   wq[(oc*WI + cw)*9 + tap],  bit i = !(w[tap][cw*64+i][oc] > 0)
// meta[oc*12 + k]: k=0..3 -> A,B,C,D (top/bot/left/right orig-popcount sums)
//                  k=4..7 -> p0,p2,p6,p8 (corner taps), k=8 -> ithr
// ---------------------------------------------------------------------------

// guaranteed fused popcount-accumulate: exactly 2 VALU inst per u64
__device__ __forceinline__ int bcnt2(u64 x, int acc) {
    int r;
    asm("v_bcnt_u32_b32 %0, %1, %3\n\t"
        "v_bcnt_u32_b32 %0, %2, %0"
        : "=&v"(r)
        : "v"((unsigned)x), "v"((unsigned)(x >> 32)), "v"(acc));
    return r;
}

// ---------------------------------------------------------------------------
// prep: (a) zero padded maps (blocks [0,1024));
//       (b) COALESCED weight pack: one wave per (layer, tap, cw, 64-oc grp);
//           lane = oc. Loop ci: consecutive lanes read consecutive oc
//           (256B coalesced, each float read once). Lane assembles its own
//           64-bit complemented mask; one store per 64 loads.
// ---------------------------------------------------------------------------
__global__ __launch_bounds__(256) void prep_kernel(
        const float* __restrict__ w2, const float* __restrict__ w3,
        const float* __restrict__ w4, const float* __restrict__ w5,
        const float* __restrict__ w6,
        u64* __restrict__ wq2, u64* __restrict__ wq3, u64* __restrict__ wq4,
        u64* __restrict__ wq5, u64* __restrict__ wq6,
        u64* __restrict__ pz, int nz) {
    const int ZB = 1024;
    if (blockIdx.x < ZB) {
        int i = blockIdx.x * 256 + threadIdx.x;
        const int stride = ZB * 256;
        for (; i < nz; i += stride) pz[i] = 0;
        return;
    }
    int wid = ((blockIdx.x - ZB) * 256 + threadIdx.x) >> 6;
    int lane = threadIdx.x & 63;
    const float* w; u64* wq; int Wi, Cout, base;
    if      (wid <   36) { w = w2; wq = wq2; Wi = 2; Cout = 128; base = 0; }
    else if (wid <  108) { w = w3; wq = wq3; Wi = 2; Cout = 256; base = 36; }
    else if (wid <  252) { w = w4; wq = wq4; Wi = 4; Cout = 256; base = 108; }
    else if (wid <  540) { w = w5; wq = wq5; Wi = 4; Cout = 512; base = 252; }
    else if (wid < 1116) { w = w6; wq = wq6; Wi = 8; Cout = 512; base = 540; }
    else return;
    int id = wid - base;
    int ng = Cout >> 6;
    int og = id % ng;
    int t2 = id / ng;
    int cw = t2 % Wi;
    int tap = t2 / Wi;
    int Cin = Wi * 64;
    const float* wp = w + ((size_t)tap * Cin + cw * 64) * Cout + og * 64 + lane;
    u64 mask = 0;
    for (int ci = 0; ci < 64; ci++) {
        float v = wp[(size_t)ci * Cout];
        mask |= (u64)(!(v > 0.0f)) << ci;
    }
    wq[((size_t)(og * 64 + lane) * Wi + cw) * 9 + tap] = mask;
}

// ---------------------------------------------------------------------------
// meta: one wave per oc (1664 waves) from PACKED weights (290 KB total).
// P_t = 64*WI - sum_cw popcount(complemented). Lane 0 stores the 8
// padding-correction sums and ithr = floor(-bias/scale) (sentinel -2^29
// when bias>0 -> bit always 1).
// ---------------------------------------------------------------------------
__global__ __launch_bounds__(256) void meta_kernel(
        const u64* __restrict__ wq2, const u64* __restrict__ wq3,
        const u64* __restrict__ wq4, const u64* __restrict__ wq5,
        const u64* __restrict__ wq6,
        const float* s2, const float* b2, const float* s3, const float* b3,
        const float* s4, const float* b4, const float* s5, const float* b5,
        const float* s6, const float* b6,
        int* __restrict__ mt) {
    int wid = (blockIdx.x * 256 + threadIdx.x) >> 6;
    int lane = threadIdx.x & 63;
    if (wid >= 1664) return;
    const u64* wq; int WI, oc, mbase; const float* sc; const float* bi;
    if      (wid <  128) { wq = wq2; WI = 2; oc = wid;        mbase = 0;     sc = s2; bi = b2; }
    else if (wid <  384) { wq = wq3; WI = 2; oc = wid - 128;  mbase = 1536;  sc = s3; bi = b3; }
    else if (wid <  640) { wq = wq4; WI = 4; oc = wid - 384;  mbase = 4608;  sc = s4; bi = b4; }
    else if (wid < 1152) { wq = wq5; WI = 4; oc = wid - 640;  mbase = 7680;  sc = s5; bi = b5; }
    else                 { wq = wq6; WI = 8; oc = wid - 1152; mbase = 13824; sc = s6; bi = b6; }
    int P = 0;
    if (lane < 9) {
        int s = 0;
        for (int cw = 0; cw < WI; cw++)
            s += (int)__popcll(wq[((size_t)oc * WI + cw) * 9 + lane]);
        P = 64 * WI - s;
    }
    int p0 = __shfl(P, 0, 64), p1 = __shfl(P, 1, 64), p2 = __shfl(P, 2, 64);
    int p3 = __shfl(P, 3, 64), p5 = __shfl(P, 5, 64);
    int p6 = __shfl(P, 6, 64), p7 = __shfl(P, 7, 64), p8 = __shfl(P, 8, 64);
    if (lane == 0) {
        int* mo = mt + mbase + oc * 12;
        mo[0] = p0 + p1 + p2;      // top
        mo[1] = p6 + p7 + p8;      // bottom
        mo[2] = p0 + p3 + p6;      // left
        mo[3] = p2 + p5 + p8;      // right
        mo[4] = p0; mo[5] = p2; mo[6] = p6; mo[7] = p8;
        double tneg = -(double)bi[oc] / (double)sc[oc];
        mo[8] = (tneg < 0.0) ? -(1 << 29) : (int)floor(tneg);
    }
}

// ---------------------------------------------------------------------------
// conv1 (float, 3->128) + b1 + relu + bn1 -> sign bits into plane-major
// padded p1. Weights in VGPRs, 8 px/thread sliding window. Double
// accumulation: sign decisions feed 5 binary layers; must be exact.
// ---------------------------------------------------------------------------
__global__ __launch_bounds__(128) void conv1_pack_kernel(
        const float* __restrict__ x, const float* __restrict__ w1,
        const float* __restrict__ b1, const float* __restrict__ s1,
        const float* __restrict__ bb1, u64* __restrict__ p1) {
    const int t = threadIdx.x;
    const int oc = t;
    const int bx = blockIdx.x;
    const int xseg = (bx & 3) << 3;    // 0,8,16,24
    const int y = (bx >> 2) & 31;
    const int b = bx >> 7;

    double wreg[27];
    #pragma unroll
    for (int k = 0; k < 27; k++) wreg[k] = (double)w1[k * 128 + oc];
    const double b1v = (double)b1[oc];
    const double tneg = -(double)bb1[oc] / (double)s1[oc];
    const bool always = tneg < 0.0;
    const double thr = tneg - b1v;

    double acc[8];
    #pragma unroll
    for (int i = 0; i < 8; i++) acc[i] = 0.0;

    #pragma unroll
    for (int ky = 0; ky < 3; ky++) {
        int iy = y - 1 + ky;
        if (iy < 0 || iy > 31) continue;
        #pragma unroll
        for (int col = 0; col < 10; col++) {
            int ix = xseg - 1 + col;
            if (ix < 0 || ix > 31) continue;
            const float* xp = x + ((b * 32 + iy) * 32 + ix) * 3;
            #pragma unroll
            for (int c = 0; c < 3; c++) {
                double xv = (double)xp[c];
                #pragma unroll
                for (int kx = 0; kx < 3; kx++) {
                    int px = col - kx;
                    if (px >= 0 && px < 8)
                        acc[px] += xv * wreg[(ky * 3 + kx) * 3 + c];
                }
            }
        }
    }
    const int w = t >> 6;   // cw plane
    #pragma unroll
    for (int px = 0; px < 8; px++) {
        bool bit = always || (acc[px] > thr);
        u64 m = __ballot(bit);
        if ((t & 63) == 0)
            p1[(((size_t)w * 128 + b) * 34 + y + 1) * 34 + xseg + px + 1] = m;
    }
}

// ---------------------------------------------------------------------------
// Binary conv v6.2 — lane = pixel, cw-outer streaming, OCG=8, asm-fused
// popcount accumulate (exactly 4 VALU per 64-MAC unit).
// One wave = 8x8 pre-pool tile x 8 channels; act[9] per cw; m[8] resident.
// Epilogue: d = 2*(m+S) - 64*WI*(9+n_oob); bit = d > ithr (int cmp);
// pooled mask = OR over window via 2 shfl_xor; byte store per group.
// ---------------------------------------------------------------------------
template<int WI, int H, int W, int COUT, bool POOL, bool BITOUT>
__global__ __launch_bounds__(256, 4) void bconv62_kernel(
        const u64* __restrict__ in, const u64* __restrict__ wq,
        const int* __restrict__ mt,
        const float* __restrict__ bns, const float* __restrict__ bnb,
        u64* __restrict__ outb, float* __restrict__ outf) {
    constexpr int OCG = 8;
    constexpr int Hp = H + 2, Wp = W + 2;
    constexpr int Ho = POOL ? H / 2 : H;
    constexpr int Wo = POOL ? W / 2 : W;
    constexpr int TX = W / 8;
    constexpr int TILES = (H / 8) * (W / 8);
    constexpr int NG = COUT / OCG;

    const int lane = threadIdx.x & 63;
    int wid = (blockIdx.x * blockDim.x + threadIdx.x) >> 6;
    wid = __builtin_amdgcn_readfirstlane(wid);
    const int g = wid % NG;
    int tb = wid / NG;
    const int tile = tb % TILES;
    const int b = tb / TILES;
    if (b >= 128) return;
    const int ly = lane >> 3, lx = lane & 7;
    const int py = (tile / TX) * 8 + ly;
    const int px = (tile % TX) * 8 + lx;
    const int oc0 = g * OCG;

    // per-lane edge flags / padding base
    const int ft = (py == 0), fb = (py == H - 1);
    const int fl = (px == 0), fr = (px == W - 1);
    const int ctl = ft & fl, ctr = ft & fr, cbl = fb & fl, cbr = fb & fr;
    const int n_oob = 3 * (ft + fb + fl + fr) - ctl - ctr - cbl - cbr;
    const int dbase = -64 * WI * (9 + n_oob);
    const bool anyedge = __ballot(ft | fb | fl | fr) != 0;

    int m[OCG];
    #pragma unroll
    for (int o = 0; o < OCG; o++) m[o] = 0;

    const u64* ab = in + ((size_t)b * Hp + py) * Wp + px;   // plane 0 base
    const u64* wb0 = wq + (size_t)oc0 * WI * 9;

    #pragma unroll 1
    for (int cw = 0; cw < WI; cw++) {
        const u64* ap = ab + (size_t)cw * (128 * Hp * Wp);
        u64 act[9];
        #pragma unroll
        for (int ky = 0; ky < 3; ky++)
            #pragma unroll
            for (int kx = 0; kx < 3; kx++)
                act[ky * 3 + kx] = ap[ky * Wp + kx];
        const u64* wb = wb0 + (size_t)cw * 9;
        #pragma unroll
        for (int o = 0; o < OCG; o++) {
            const u64* wl = wb + (size_t)o * (WI * 9);   // uniform -> s_load
            int acc = m[o];
            #pragma unroll
            for (int t9 = 0; t9 < 9; t9++)
                acc = bcnt2(act[t9] ^ wl[t9], acc);      // 4 VALU / unit
            m[o] = acc;
        }
    }

    // ---- epilogue ----
    const bool master = POOL ? (((ly | lx) & 1) == 0) : true;
    const int opy = POOL ? (py >> 1) : py, opx = POOL ? (px >> 1) : px;
    unsigned mask = 0;

    #pragma unroll
    for (int o = 0; o < OCG; o++) {
        const int* mo = mt + (size_t)(oc0 + o) * 12;
        int d;
        if (anyedge) {
            int S = ft * mo[0] + fb * mo[1] + fl * mo[2] + fr * mo[3]
                  - ctl * mo[4] - ctr * mo[5] - cbl * mo[6] - cbr * mo[7];
            d = 2 * (m[o] + S) + dbase;
        } else {
            d = 2 * m[o] - 64 * WI * 9;
        }
        if constexpr (BITOUT) {
            mask |= (unsigned)(d > mo[8]) << o;
        } else {
            int dm = max(d, __shfl_xor(d, 1, 64));
            int dp = max(dm, __shfl_xor(dm, 8, 64));
            int pmax = dp > 0 ? dp : 0;
            float h = (float)pmax * bns[oc0 + o] + bnb[oc0 + o];
            if (master)
                outf[(size_t)((b * 4 + opy) * 4 + opx) * 512 + oc0 + o] = h;
        }
    }

    if constexpr (BITOUT) {
        if constexpr (POOL) {
            mask |= __shfl_xor(mask, 1, 64);
            mask |= __shfl_xor(mask, 8, 64);
        }
        if (master) {
            size_t idx = (((size_t)(oc0 >> 6) * 128 + b) * (Ho + 2) + opy + 1)
                         * (Wo + 2) + opx + 1;
            char* bp = (char*)(outb + idx) + ((oc0 & 63) >> 3);
            *(unsigned char*)bp = (unsigned char)mask;
        }
    }
}

// ---------------------------------------------------------------------------
// Dense (512x10) + softmax. One wave per row. 2048 rows.
// ---------------------------------------------------------------------------
__global__ __launch_bounds__(256) void dense_softmax_kernel(
        const float* __restrict__ h6, const float* __restrict__ dw,
        const float* __restrict__ db, float* __restrict__ out) {
    int lane = threadIdx.x & 63;
    int r = (blockIdx.x * blockDim.x + threadIdx.x) >> 6;
    if (r >= 2048) return;
    const float* hr = h6 + (size_t)r * 512;
    float part[10];
    #pragma unroll
    for (int d = 0; d < 10; d++) part[d] = 0.f;
    #pragma unroll
    for (int k = 0; k < 8; k++) {
        int c = lane + 64 * k;
        float hv = hr[c];
        const float* dwr = dw + c * 10;
        #pragma unroll
        for (int d = 0; d < 10; d++) part[d] += hv * dwr[d];
    }
    #pragma unroll
    for (int off = 32; off >= 1; off >>= 1) {
        #pragma unroll
        for (int d = 0; d < 10; d++) part[d] += __shfl_down(part[d], off, 64);
    }
    if (lane == 0) {
        float logits[10];
        float mx = -1e30f;
        #pragma unroll
        for (int d = 0; d < 10; d++) { logits[d] = part[d] + db[d]; mx = fmaxf(mx, logits[d]); }
        float se = 0.f;
        #pragma unroll
        for (int d = 0; d < 10; d++) { logits[d] = expf(logits[d] - mx); se += logits[d]; }
        float inv = 1.f / se;
        #pragma unroll
        for (int d = 0; d < 10; d++) out[(size_t)r * 10 + d] = logits[d] * inv;
    }
}

// ---------------------------------------------------------------------------
extern "C" void kernel_launch(void* const* d_in, const int* in_sizes, int n_in,
                              void* d_out, int out_size, void* d_ws, size_t ws_size,
                              hipStream_t stream) {
    const float* x    = (const float*)d_in[0];
    const float* w1   = (const float*)d_in[1];
    const float* b1   = (const float*)d_in[2];
    const float* w2   = (const float*)d_in[3];
    const float* w3   = (const float*)d_in[4];
    const float* w4   = (const float*)d_in[5];
    const float* w5   = (const float*)d_in[6];
    const float* w6   = (const float*)d_in[7];
    const float* bn1s = (const float*)d_in[8];
    const float* bn1b = (const float*)d_in[9];
    const float* bn2s = (const float*)d_in[10];
    const float* bn2b = (const float*)d_in[11];
    const float* bn3s = (const float*)d_in[12];
    const float* bn3b = (const float*)d_in[13];
    const float* bn4s = (const float*)d_in[14];
    const float* bn4b = (const float*)d_in[15];
    const float* bn5s = (const float*)d_in[16];
    const float* bn5b = (const float*)d_in[17];
    const float* bn6s = (const float*)d_in[18];
    const float* bn6b = (const float*)d_in[19];
    const float* dw   = (const float*)d_in[20];
    const float* db   = (const float*)d_in[21];
    float* out = (float*)d_out;

    // workspace (u64 units)
    u64* ws   = (u64*)d_ws;
    u64* wq2  = ws;                    // 2304
    u64* wq3  = ws + 2304;             // 4608
    u64* wq4  = ws + 6912;             // 9216
    u64* wq5  = ws + 16128;            // 18432
    u64* wq6  = ws + 34560;            // 36864
    int* mt   = (int*)(ws + 71424);    // 19968 ints = 9984 u64
    u64* p1   = ws + 81408;            // 2*128*34*34 = 295936
    u64* p2   = ws + 377344;           // 2*128*18*18 = 82944
    u64* p3   = ws + 460288;           // 4*128*18*18 = 165888
    u64* p4   = ws + 626176;           // 4*128*10*10 = 51200
    u64* p5   = ws + 677376;           // 8*128*10*10 = 102400
    float* h6 = (float*)(ws + 779776); // 128*4*4*512 floats
    const int NPAD = 295936 + 82944 + 165888 + 51200 + 102400;  // 698368

    int* mt2 = mt + 0;
    int* mt3 = mt + 1536;
    int* mt4 = mt + 4608;
    int* mt5 = mt + 7680;
    int* mt6 = mt + 13824;

    // prep: zero maps (1024 blocks) + coalesced pack (1116 waves = 279 blocks)
    prep_kernel<<<1024 + 279, 256, 0, stream>>>(
        w2, w3, w4, w5, w6, wq2, wq3, wq4, wq5, wq6, p1, NPAD);
    // meta from packed weights (290 KB)
    meta_kernel<<<416, 256, 0, stream>>>(wq2, wq3, wq4, wq5, wq6,
        bn2s, bn2b, bn3s, bn3b, bn4s, bn4b, bn5s, bn5b, bn6s, bn6b, mt);

    conv1_pack_kernel<<<128*32*4, 128, 0, stream>>>(x, w1, b1, bn1s, bn1b, p1);

    // waves = 128 * tiles/img * (COUT/8); blocks = waves/4
    bconv62_kernel<2,32,32,128,true, true ><<<8192, 256, 0, stream>>>(p1, wq2, mt2, nullptr, nullptr, p2, nullptr);
    bconv62_kernel<2,16,16,256,false,true ><<<4096, 256, 0, stream>>>(p2, wq3, mt3, nullptr, nullptr, p3, nullptr);
    bconv62_kernel<4,16,16,256,true, true ><<<4096, 256, 0, stream>>>(p3, wq4, mt4, nullptr, nullptr, p4, nullptr);
    bconv62_kernel<4,8,8,  512,false,true ><<<2048, 256, 0, stream>>>(p4, wq5, mt5, nullptr, nullptr, p5, nullptr);
    bconv62_kernel<8,8,8,  512,true, false><<<2048, 256, 0, stream>>>(p5, wq6, mt6, bn6s, bn6b, nullptr, h6);

    dense_softmax_kernel<<<512, 256, 0, stream>>>(h6, dw, db, out);
}

// Round 14
// 309.131 us; speedup vs baseline: 1.1747x; 1.0337x over previous
//
#include <hip/hip_runtime.h>
#include <cstdint>
#include <math.h>

typedef unsigned long long u64;

// ---------------------------------------------------------------------------
// Activation bit-maps are CW-PLANE-MAJOR and zero-padded:
//   map[((cw*128 + b)*Hp + y)*Wp + x],  Hp=H+2, Wp=W+2, halo = 0
// Weights packed COMPLEMENTED, per-oc contiguous:
//   wq[(oc*WI + cw)*9 + tap],  bit i = !(w[tap][cw*64+i][oc] > 0)
// meta[oc*12 + k]: k=0..3 -> A,B,C,D (top/bot/left/right orig-popcount sums)
//                  k=4..7 -> p0,p2,p6,p8 (corner taps), k=8 -> ithr
// ---------------------------------------------------------------------------

// guaranteed fused popcount-accumulate: exactly 2 VALU inst per u64
__device__ __forceinline__ int bcnt2(u64 x, int acc) {
    int r;
    asm("v_bcnt_u32_b32 %0, %1, %3\n\t"
        "v_bcnt_u32_b32 %0, %2, %0"
        : "=&v"(r)
        : "v"((unsigned)x), "v"((unsigned)(x >> 32)), "v"(acc));
    return r;
}

// ---------------------------------------------------------------------------
// prep: (a) zero padded maps (blocks [0,1024));
//       (b) COALESCED weight pack: one wave per (layer, tap, cw, 64-oc grp);
//           lane = oc; each float read exactly once (256B coalesced rows).
// ---------------------------------------------------------------------------
__global__ __launch_bounds__(256) void prep_kernel(
        const float* __restrict__ w2, const float* __restrict__ w3,
        const float* __restrict__ w4, const float* __restrict__ w5,
        const float* __restrict__ w6,
        u64* __restrict__ wq2, u64* __restrict__ wq3, u64* __restrict__ wq4,
        u64* __restrict__ wq5, u64* __restrict__ wq6,
        u64* __restrict__ pz, int nz) {
    const int ZB = 1024;
    if (blockIdx.x < ZB) {
        int i = blockIdx.x * 256 + threadIdx.x;
        const int stride = ZB * 256;
        for (; i < nz; i += stride) pz[i] = 0;
        return;
    }
    int wid = ((blockIdx.x - ZB) * 256 + threadIdx.x) >> 6;
    int lane = threadIdx.x & 63;
    const float* w; u64* wq; int Wi, Cout, base;
    if      (wid <   36) { w = w2; wq = wq2; Wi = 2; Cout = 128; base = 0; }
    else if (wid <  108) { w = w3; wq = wq3; Wi = 2; Cout = 256; base = 36; }
    else if (wid <  252) { w = w4; wq = wq4; Wi = 4; Cout = 256; base = 108; }
    else if (wid <  540) { w = w5; wq = wq5; Wi = 4; Cout = 512; base = 252; }
    else if (wid < 1116) { w = w6; wq = wq6; Wi = 8; Cout = 512; base = 540; }
    else return;
    int id = wid - base;
    int ng = Cout >> 6;
    int og = id % ng;
    int t2 = id / ng;
    int cw = t2 % Wi;
    int tap = t2 / Wi;
    int Cin = Wi * 64;
    const float* wp = w + ((size_t)tap * Cin + cw * 64) * Cout + og * 64 + lane;
    u64 mask = 0;
    for (int ci = 0; ci < 64; ci++) {
        float v = wp[(size_t)ci * Cout];
        mask |= (u64)(!(v > 0.0f)) << ci;
    }
    wq[((size_t)(og * 64 + lane) * Wi + cw) * 9 + tap] = mask;
}

// ---------------------------------------------------------------------------
// meta: one wave per oc (1664 waves) from PACKED weights (290 KB total).
// ---------------------------------------------------------------------------
__global__ __launch_bounds__(256) void meta_kernel(
        const u64* __restrict__ wq2, const u64* __restrict__ wq3,
        const u64* __restrict__ wq4, const u64* __restrict__ wq5,
        const u64* __restrict__ wq6,
        const float* s2, const float* b2, const float* s3, const float* b3,
        const float* s4, const float* b4, const float* s5, const float* b5,
        const float* s6, const float* b6,
        int* __restrict__ mt) {
    int wid = (blockIdx.x * 256 + threadIdx.x) >> 6;
    int lane = threadIdx.x & 63;
    if (wid >= 1664) return;
    const u64* wq; int WI, oc, mbase; const float* sc; const float* bi;
    if      (wid <  128) { wq = wq2; WI = 2; oc = wid;        mbase = 0;     sc = s2; bi = b2; }
    else if (wid <  384) { wq = wq3; WI = 2; oc = wid - 128;  mbase = 1536;  sc = s3; bi = b3; }
    else if (wid <  640) { wq = wq4; WI = 4; oc = wid - 384;  mbase = 4608;  sc = s4; bi = b4; }
    else if (wid < 1152) { wq = wq5; WI = 4; oc = wid - 640;  mbase = 7680;  sc = s5; bi = b5; }
    else                 { wq = wq6; WI = 8; oc = wid - 1152; mbase = 13824; sc = s6; bi = b6; }
    int P = 0;
    if (lane < 9) {
        int s = 0;
        for (int cw = 0; cw < WI; cw++)
            s += (int)__popcll(wq[((size_t)oc * WI + cw) * 9 + lane]);
        P = 64 * WI - s;
    }
    int p0 = __shfl(P, 0, 64), p1 = __shfl(P, 1, 64), p2 = __shfl(P, 2, 64);
    int p3 = __shfl(P, 3, 64), p5 = __shfl(P, 5, 64);
    int p6 = __shfl(P, 6, 64), p7 = __shfl(P, 7, 64), p8 = __shfl(P, 8, 64);
    if (lane == 0) {
        int* mo = mt + mbase + oc * 12;
        mo[0] = p0 + p1 + p2;      // top
        mo[1] = p6 + p7 + p8;      // bottom
        mo[2] = p0 + p3 + p6;      // left
        mo[3] = p2 + p5 + p8;      // right
        mo[4] = p0; mo[5] = p2; mo[6] = p6; mo[7] = p8;
        double tneg = -(double)bi[oc] / (double)sc[oc];
        mo[8] = (tneg < 0.0) ? -(1 << 29) : (int)floor(tneg);
    }
}

// ---------------------------------------------------------------------------
// conv1 (float, 3->128) + b1 + relu + bn1 -> sign bits into plane-major
// padded p1. Weights in VGPRs, 8 px/thread sliding window. Double
// accumulation: sign decisions feed 5 binary layers; must be exact.
// ---------------------------------------------------------------------------
__global__ __launch_bounds__(128) void conv1_pack_kernel(
        const float* __restrict__ x, const float* __restrict__ w1,
        const float* __restrict__ b1, const float* __restrict__ s1,
        const float* __restrict__ bb1, u64* __restrict__ p1) {
    const int t = threadIdx.x;
    const int oc = t;
    const int bx = blockIdx.x;
    const int xseg = (bx & 3) << 3;    // 0,8,16,24
    const int y = (bx >> 2) & 31;
    const int b = bx >> 7;

    double wreg[27];
    #pragma unroll
    for (int k = 0; k < 27; k++) wreg[k] = (double)w1[k * 128 + oc];
    const double b1v = (double)b1[oc];
    const double tneg = -(double)bb1[oc] / (double)s1[oc];
    const bool always = tneg < 0.0;
    const double thr = tneg - b1v;

    double acc[8];
    #pragma unroll
    for (int i = 0; i < 8; i++) acc[i] = 0.0;

    #pragma unroll
    for (int ky = 0; ky < 3; ky++) {
        int iy = y - 1 + ky;
        if (iy < 0 || iy > 31) continue;
        #pragma unroll
        for (int col = 0; col < 10; col++) {
            int ix = xseg - 1 + col;
            if (ix < 0 || ix > 31) continue;
            const float* xp = x + ((b * 32 + iy) * 32 + ix) * 3;
            #pragma unroll
            for (int c = 0; c < 3; c++) {
                double xv = (double)xp[c];
                #pragma unroll
                for (int kx = 0; kx < 3; kx++) {
                    int px = col - kx;
                    if (px >= 0 && px < 8)
                        acc[px] += xv * wreg[(ky * 3 + kx) * 3 + c];
                }
            }
        }
    }
    const int w = t >> 6;   // cw plane
    #pragma unroll
    for (int px = 0; px < 8; px++) {
        bool bit = always || (acc[px] > thr);
        u64 m = __ballot(bit);
        if ((t & 63) == 0)
            p1[(((size_t)w * 128 + b) * 34 + y + 1) * 34 + xseg + px + 1] = m;
    }
}

// ---------------------------------------------------------------------------
// Binary conv v6.3 — lane = pixel, cw-outer streaming, OCG=8, IMAGE-PAIRED:
// each lane processes the same pixel of images (2t, 2t+1). Weight s_loads,
// preamble, edge flags, meta loads and S-correction amortize over 2 units;
// waves halve. Dot = asm-fused bcnt (4 VALU / 64-MAC unit).
// ---------------------------------------------------------------------------
template<int WI, int H, int W, int COUT, bool POOL, bool BITOUT>
__global__ __launch_bounds__(256, 3) void bconv63_kernel(
        const u64* __restrict__ in, const u64* __restrict__ wq,
        const int* __restrict__ mt,
        const float* __restrict__ bns, const float* __restrict__ bnb,
        u64* __restrict__ outb, float* __restrict__ outf) {
    constexpr int OCG = 8;
    constexpr int Hp = H + 2, Wp = W + 2;
    constexpr int Ho = POOL ? H / 2 : H;
    constexpr int Wo = POOL ? W / 2 : W;
    constexpr int TX = W / 8;
    constexpr int TILES = (H / 8) * (W / 8);
    constexpr int NG = COUT / OCG;

    const int lane = threadIdx.x & 63;
    int wid = (blockIdx.x * blockDim.x + threadIdx.x) >> 6;
    wid = __builtin_amdgcn_readfirstlane(wid);
    const int g = wid % NG;
    int tb = wid / NG;
    const int tile = tb % TILES;
    const int pr = tb / TILES;      // image pair 0..63
    if (pr >= 64) return;
    const int b0 = pr * 2, b1 = b0 + 1;
    const int ly = lane >> 3, lx = lane & 7;
    const int py = (tile / TX) * 8 + ly;
    const int px = (tile % TX) * 8 + lx;
    const int oc0 = g * OCG;

    // per-lane edge flags / padding base (shared by both images)
    const int ft = (py == 0), fb = (py == H - 1);
    const int fl = (px == 0), fr = (px == W - 1);
    const int ctl = ft & fl, ctr = ft & fr, cbl = fb & fl, cbr = fb & fr;
    const int n_oob = 3 * (ft + fb + fl + fr) - ctl - ctr - cbl - cbr;
    const int dbase = -64 * WI * (9 + n_oob);
    const bool anyedge = __ballot(ft | fb | fl | fr) != 0;

    int mA[OCG], mB[OCG];
    #pragma unroll
    for (int o = 0; o < OCG; o++) { mA[o] = 0; mB[o] = 0; }

    const u64* abA = in + ((size_t)b0 * Hp + py) * Wp + px;   // plane-0 bases
    const u64* abB = in + ((size_t)b1 * Hp + py) * Wp + px;
    const u64* wb0 = wq + (size_t)oc0 * WI * 9;

    #pragma unroll 1
    for (int cw = 0; cw < WI; cw++) {
        const u64* apA = abA + (size_t)cw * (128 * Hp * Wp);
        const u64* apB = abB + (size_t)cw * (128 * Hp * Wp);
        u64 aA[9], aB[9];
        #pragma unroll
        for (int ky = 0; ky < 3; ky++)
            #pragma unroll
            for (int kx = 0; kx < 3; kx++) {
                aA[ky * 3 + kx] = apA[ky * Wp + kx];
                aB[ky * 3 + kx] = apB[ky * Wp + kx];
            }
        const u64* wb = wb0 + (size_t)cw * 9;
        #pragma unroll
        for (int o = 0; o < OCG; o++) {
            const u64* wl = wb + (size_t)o * (WI * 9);   // uniform -> s_load
            int accA = mA[o], accB = mB[o];
            #pragma unroll
            for (int t9 = 0; t9 < 9; t9++) {
                u64 wv = wl[t9];
                accA = bcnt2(aA[t9] ^ wv, accA);
                accB = bcnt2(aB[t9] ^ wv, accB);
            }
            mA[o] = accA; mB[o] = accB;
        }
    }

    // ---- epilogue ----
    const bool master = POOL ? (((ly | lx) & 1) == 0) : true;
    const int opy = POOL ? (py >> 1) : py, opx = POOL ? (px >> 1) : px;
    unsigned maskA = 0, maskB = 0;

    #pragma unroll
    for (int o = 0; o < OCG; o++) {
        const int* mo = mt + (size_t)(oc0 + o) * 12;
        int S = 0;
        if (anyedge)
            S = ft * mo[0] + fb * mo[1] + fl * mo[2] + fr * mo[3]
              - ctl * mo[4] - ctr * mo[5] - cbl * mo[6] - cbr * mo[7];
        int dA = 2 * (mA[o] + S) + dbase;
        int dB = 2 * (mB[o] + S) + dbase;
        if constexpr (BITOUT) {
            maskA |= (unsigned)(dA > mo[8]) << o;
            maskB |= (unsigned)(dB > mo[8]) << o;
        } else {
            int dmA = max(dA, __shfl_xor(dA, 1, 64));
            int dpA = max(dmA, __shfl_xor(dmA, 8, 64));
            int dmB = max(dB, __shfl_xor(dB, 1, 64));
            int dpB = max(dmB, __shfl_xor(dmB, 8, 64));
            int pmA = dpA > 0 ? dpA : 0;
            int pmB = dpB > 0 ? dpB : 0;
            float sc = bns[oc0 + o], bi = bnb[oc0 + o];
            if (master) {
                outf[(size_t)((b0 * 4 + opy) * 4 + opx) * 512 + oc0 + o] = (float)pmA * sc + bi;
                outf[(size_t)((b1 * 4 + opy) * 4 + opx) * 512 + oc0 + o] = (float)pmB * sc + bi;
            }
        }
    }

    if constexpr (BITOUT) {
        if constexpr (POOL) {
            maskA |= __shfl_xor(maskA, 1, 64);
            maskA |= __shfl_xor(maskA, 8, 64);
            maskB |= __shfl_xor(maskB, 1, 64);
            maskB |= __shfl_xor(maskB, 8, 64);
        }
        if (master) {
            size_t idxA = (((size_t)(oc0 >> 6) * 128 + b0) * (Ho + 2) + opy + 1)
                          * (Wo + 2) + opx + 1;
            size_t idxB = (((size_t)(oc0 >> 6) * 128 + b1) * (Ho + 2) + opy + 1)
                          * (Wo + 2) + opx + 1;
            *((unsigned char*)(outb + idxA) + ((oc0 & 63) >> 3)) = (unsigned char)maskA;
            *((unsigned char*)(outb + idxB) + ((oc0 & 63) >> 3)) = (unsigned char)maskB;
        }
    }
}

// ---------------------------------------------------------------------------
// Dense (512x10) + softmax. One wave per row. 2048 rows.
// ---------------------------------------------------------------------------
__global__ __launch_bounds__(256) void dense_softmax_kernel(
        const float* __restrict__ h6, const float* __restrict__ dw,
        const float* __restrict__ db, float* __restrict__ out) {
    int lane = threadIdx.x & 63;
    int r = (blockIdx.x * blockDim.x + threadIdx.x) >> 6;
    if (r >= 2048) return;
    const float* hr = h6 + (size_t)r * 512;
    float part[10];
    #pragma unroll
    for (int d = 0; d < 10; d++) part[d] = 0.f;
    #pragma unroll
    for (int k = 0; k < 8; k++) {
        int c = lane + 64 * k;
        float hv = hr[c];
        const float* dwr = dw + c * 10;
        #pragma unroll
        for (int d = 0; d < 10; d++) part[d] += hv * dwr[d];
    }
    #pragma unroll
    for (int off = 32; off >= 1; off >>= 1) {
        #pragma unroll
        for (int d = 0; d < 10; d++) part[d] += __shfl_down(part[d], off, 64);
    }
    if (lane == 0) {
        float logits[10];
        float mx = -1e30f;
        #pragma unroll
        for (int d = 0; d < 10; d++) { logits[d] = part[d] + db[d]; mx = fmaxf(mx, logits[d]); }
        float se = 0.f;
        #pragma unroll
        for (int d = 0; d < 10; d++) { logits[d] = expf(logits[d] - mx); se += logits[d]; }
        float inv = 1.f / se;
        #pragma unroll
        for (int d = 0; d < 10; d++) out[(size_t)r * 10 + d] = logits[d] * inv;
    }
}

// ---------------------------------------------------------------------------
extern "C" void kernel_launch(void* const* d_in, const int* in_sizes, int n_in,
                              void* d_out, int out_size, void* d_ws, size_t ws_size,
                              hipStream_t stream) {
    const float* x    = (const float*)d_in[0];
    const float* w1   = (const float*)d_in[1];
    const float* b1   = (const float*)d_in[2];
    const float* w2   = (const float*)d_in[3];
    const float* w3   = (const float*)d_in[4];
    const float* w4   = (const float*)d_in[5];
    const float* w5   = (const float*)d_in[6];
    const float* w6   = (const float*)d_in[7];
    const float* bn1s = (const float*)d_in[8];
    const float* bn1b = (const float*)d_in[9];
    const float* bn2s = (const float*)d_in[10];
    const float* bn2b = (const float*)d_in[11];
    const float* bn3s = (const float*)d_in[12];
    const float* bn3b = (const float*)d_in[13];
    const float* bn4s = (const float*)d_in[14];
    const float* bn4b = (const float*)d_in[15];
    const float* bn5s = (const float*)d_in[16];
    const float* bn5b = (const float*)d_in[17];
    const float* bn6s = (const float*)d_in[18];
    const float* bn6b = (const float*)d_in[19];
    const float* dw   = (const float*)d_in[20];
    const float* db   = (const float*)d_in[21];
    float* out = (float*)d_out;

    // workspace (u64 units)
    u64* ws   = (u64*)d_ws;
    u64* wq2  = ws;                    // 2304
    u64* wq3  = ws + 2304;             // 4608
    u64* wq4  = ws + 6912;             // 9216
    u64* wq5  = ws + 16128;            // 18432
    u64* wq6  = ws + 34560;            // 36864
    int* mt   = (int*)(ws + 71424);    // 19968 ints = 9984 u64
    u64* p1   = ws + 81408;            // 2*128*34*34 = 295936
    u64* p2   = ws + 377344;           // 2*128*18*18 = 82944
    u64* p3   = ws + 460288;           // 4*128*18*18 = 165888
    u64* p4   = ws + 626176;           // 4*128*10*10 = 51200
    u64* p5   = ws + 677376;           // 8*128*10*10 = 102400
    float* h6 = (float*)(ws + 779776); // 128*4*4*512 floats
    const int NPAD = 295936 + 82944 + 165888 + 51200 + 102400;  // 698368

    int* mt2 = mt + 0;
    int* mt3 = mt + 1536;
    int* mt4 = mt + 4608;
    int* mt5 = mt + 7680;
    int* mt6 = mt + 13824;

    // prep: zero maps (1024 blocks) + coalesced pack (1116 waves = 279 blocks)
    prep_kernel<<<1024 + 279, 256, 0, stream>>>(
        w2, w3, w4, w5, w6, wq2, wq3, wq4, wq5, wq6, p1, NPAD);
    // meta from packed weights (290 KB)
    meta_kernel<<<416, 256, 0, stream>>>(wq2, wq3, wq4, wq5, wq6,
        bn2s, bn2b, bn3s, bn3b, bn4s, bn4b, bn5s, bn5b, bn6s, bn6b, mt);

    conv1_pack_kernel<<<128*32*4, 128, 0, stream>>>(x, w1, b1, bn1s, bn1b, p1);

    // waves = 64 pairs * tiles/img * (COUT/8); blocks = waves/4
    bconv63_kernel<2,32,32,128,true, true ><<<4096, 256, 0, stream>>>(p1, wq2, mt2, nullptr, nullptr, p2, nullptr);
    bconv63_kernel<2,16,16,256,false,true ><<<2048, 256, 0, stream>>>(p2, wq3, mt3, nullptr, nullptr, p3, nullptr);
    bconv63_kernel<4,16,16,256,true, true ><<<2048, 256, 0, stream>>>(p3, wq4, mt4, nullptr, nullptr, p4, nullptr);
    bconv63_kernel<4,8,8,  512,false,true ><<<1024, 256, 0, stream>>>(p4, wq5, mt5, nullptr, nullptr, p5, nullptr);
    bconv63_kernel<8,8,8,  512,true, false><<<1024, 256, 0, stream>>>(p5, wq6, mt6, bn6s, bn6b, nullptr, h6);

    dense_softmax_kernel<<<512, 256, 0, stream>>>(h6, dw, db, out);
}